// Round 7
// baseline (185.293 us; speedup 1.0000x reference)
//
#include <hip/hip_runtime.h>
#include <math.h>

#define T_LEN    20000
#define NBC      1280      // 32*40 sequences, one block each
#define NTHREADS 256
#define CS       16        // elements per thread per round
#define ACT      250       // active chunks per round
#define TILE     (ACT*CS)  // 4000 elements per round
#define ROUNDS   5         // 5*4000 = 20000

// Immediate permeability:
//   ppi = (p3/p1) * log1p(exp(p1*x)),  p1 = ln2*(PIMAX/PIREST) = 50*ln2
// Base-2 identity (valid for ALL x, branch-free):
//   ppi = 0.012 * log2(1 + 2^(50x)) = 0.012 * (50x + log2(1 + 2^(-50x)))
__device__ __forceinline__ float softplus_ppi(float x) {
    float y = 50.0f * x;
    float t = __builtin_exp2f(-y);        // v_exp_f32
    float l = __builtin_log2f(1.0f + t);  // v_log_f32
    return 0.012f * (y + l);
}

__global__ __launch_bounds__(NTHREADS, 5)   // cap VGPR so 5 blocks/CU stay resident
void na_scan_kernel(const float* __restrict__ ihcl, float* __restrict__ out) {
    const int bc  = blockIdx.x;
    const int tid = threadIdx.x;
    const long base = (long)bc * T_LEN;

    // reference constants: a_i = 0.1, a_l = 0.01
    const float A_I = 0.1f;
    const float A_L = 0.01f;
    const float PLc = 0.06f;
    const float PGc = 0.03f;
    const float BE  = A_I * PLc;                  // 0.006
    const float GA  = A_L * PLc;                  // 0.0006
    const float DE  = 1.0f - A_L * (PLc + PGc);   // 0.9991
    const float CI0 = 4166.666666666667f;         // SPONT/PIREST
    const float CL0 = 5000.0f;
    const float CG  = 6666.6669921875f;           // f32-exact per reference
    const float CLC = A_L * PGc * CG;

    __shared__ float s0[NTHREADS], s1[NTHREADS], s2[NTHREADS],
                     s3[NTHREADS], s4[NTHREADS], s5[NTHREADS];

    float CIr = CI0, CLr = CL0;        // running state entering current round
    const bool active = (tid < ACT);

    for (int r = 0; r < ROUNDS; ++r) {
        const int t0 = r * TILE + tid * CS;

        // ---- fused pass 1: compose chunk map, keep per-element CI-row coeffs ----
        float m00 = 1.f, m01 = 0.f, m10 = 0.f, m11 = 1.f, v0 = 0.f, v1 = 0.f;
        float c0[CS], c1[CS], cv[CS], cp[CS];

        if (active) {
            const float4* src = reinterpret_cast<const float4*>(ihcl + base + t0);
            float4 q0 = src[0], q1 = src[1], q2 = src[2], q3 = src[3];
            float xs[CS] = {q0.x,q0.y,q0.z,q0.w, q1.x,q1.y,q1.z,q1.w,
                            q2.x,q2.y,q2.z,q2.w, q3.x,q3.y,q3.z,q3.w};
            #pragma unroll
            for (int e = 0; e < CS; ++e) {
                float ppi = softplus_ppi(xs[e]);
                bool skip = (e == 0) && (r == 0) && (tid == 0);  // global t=0: identity
                if (!skip) {
                    float al = 1.0f - A_I * (ppi + PLc);
                    // A = [[al, BE], [GA*al, GA*BE + DE]], b = (0, CLC)
                    float nm00 = al * m00 + BE * m10;
                    float nm01 = al * m01 + BE * m11;
                    float nv0  = al * v0  + BE * v1;
                    m10 = GA * nm00 + DE * m10;
                    m11 = GA * nm01 + DE * m11;
                    v1  = GA * nv0  + DE * v1 + CLC;
                    m00 = nm00; m01 = nm01; v0 = nv0;
                }
                c0[e] = m00; c1[e] = m01; cv[e] = v0; cp[e] = ppi;
            }
        }

        // ---- block scan of affine maps (Hillis-Steele over 256; 250..255 identity) ----
        s0[tid]=m00; s1[tid]=m01; s2[tid]=m10; s3[tid]=m11; s4[tid]=v0; s5[tid]=v1;
        __syncthreads();
        for (int d = 1; d < NTHREADS; d <<= 1) {
            float a00=0.f,a01=0.f,a10=0.f,a11=0.f,av0=0.f,av1=0.f;
            const bool act2 = (tid >= d);
            if (act2) { a00=s0[tid-d]; a01=s1[tid-d]; a10=s2[tid-d];
                        a11=s3[tid-d]; av0=s4[tid-d]; av1=s5[tid-d]; }
            __syncthreads();
            if (act2) {
                float r00 = m00*a00 + m01*a10;
                float r01 = m00*a01 + m01*a11;
                float r10 = m10*a00 + m11*a10;
                float r11 = m10*a01 + m11*a11;
                float rv0 = m00*av0 + m01*av1 + v0;
                float rv1 = m10*av0 + m11*av1 + v1;
                m00=r00; m01=r01; m10=r10; m11=r11; v0=rv0; v1=rv1;
                s0[tid]=m00; s1[tid]=m01; s2[tid]=m10; s3[tid]=m11; s4[tid]=v0; s5[tid]=v1;
            }
            __syncthreads();
        }

        // start state of my chunk = exclusive prefix applied to running state
        float CIs = CIr, CLs = CLr;
        if (tid > 0) {
            float e00=s0[tid-1], e01=s1[tid-1], e10=s2[tid-1],
                  e11=s3[tid-1], ev0=s4[tid-1], ev1=s5[tid-1];
            CIs = e00*CIr + e01*CLr + ev0;
            CLs = e10*CIr + e11*CLr + ev1;
        }
        // tile total (entries 250..255 are identity, so [255] == [249])
        float T00=s0[NTHREADS-1], T01=s1[NTHREADS-1], T10=s2[NTHREADS-1],
              T11=s3[NTHREADS-1], Tv0=s4[NTHREADS-1], Tv1=s5[NTHREADS-1];
        float nCIr = T00*CIr + T01*CLr + Tv0;
        float nCLr = T10*CIr + T11*CLr + Tv1;

        // ---- epilogue: out_e = ppi_e * (m00_e*CIs + m01_e*CLs + v0_e), no replay ----
        if (active) {
            float os[CS];
            #pragma unroll
            for (int e = 0; e < CS; ++e)
                os[e] = cp[e] * (c0[e]*CIs + c1[e]*CLs + cv[e]);
            if (r == 0 && tid == 0) os[0] = 50.0f;   // t = 0 stays at spont
            float4* dst = reinterpret_cast<float4*>(out + base + t0);
            dst[0] = make_float4(os[0], os[1], os[2], os[3]);
            dst[1] = make_float4(os[4], os[5], os[6], os[7]);
            dst[2] = make_float4(os[8], os[9], os[10],os[11]);
            dst[3] = make_float4(os[12],os[13],os[14],os[15]);
        }

        CIr = nCIr; CLr = nCLr;
        __syncthreads();   // protect scan arrays before next round's writes
    }
}

extern "C" void kernel_launch(void* const* d_in, const int* in_sizes, int n_in,
                              void* d_out, int out_size, void* d_ws, size_t ws_size,
                              hipStream_t stream) {
    const float* ihcl = (const float*)d_in[0];
    float* out = (float*)d_out;
    na_scan_kernel<<<NBC, NTHREADS, 0, stream>>>(ihcl, out);
}

// Round 8
// 57.377 us; speedup vs baseline: 3.2294x; 3.2294x over previous
//
#include <hip/hip_runtime.h>
#include <math.h>

#define T_LEN    20000
#define NBC      1280      // 32*40 sequences, one block each
#define NTHREADS 256
#define CS       16        // elements per thread per round
#define ACT      250       // active threads per round
#define TILE     (ACT*CS)  // 4000 elements per round
#define ROUNDS   5         // 5*4000 = 20000

// Immediate permeability:
//   ppi = (p3/p1) * log1p(exp(p1*x)),  p1 = ln2*(PIMAX/PIREST) = 50*ln2
// Base-2 identity (valid for ALL x, branch-free):
//   ppi = 0.012 * log2(1 + 2^(50x)) = 0.012 * (50x + log2(1 + 2^(-50x)))
__device__ __forceinline__ float softplus_ppi(float x) {
    float y = 50.0f * x;
    float t = __builtin_exp2f(-y);        // v_exp_f32
    float l = __builtin_log2f(1.0f + t);  // v_log_f32
    return 0.012f * (y + l);
}

__global__ __launch_bounds__(NTHREADS, 5)   // 5 blocks/CU -> all 1280 resident
void na_scan_kernel(const float* __restrict__ ihcl, float* __restrict__ out) {
    const int bc   = blockIdx.x;
    const int tid  = threadIdx.x;
    const int lane = tid & 63;
    const int wv   = tid >> 6;             // wave id 0..3
    const long base = (long)bc * T_LEN;

    // reference constants: a_i = 0.1, a_l = 0.01
    const float A_I = 0.1f;
    const float A_L = 0.01f;
    const float PLc = 0.06f;
    const float PGc = 0.03f;
    const float BE  = A_I * PLc;                  // 0.006
    const float GA  = A_L * PLc;                  // 0.0006
    const float DE  = 1.0f - A_L * (PLc + PGc);   // 0.9991
    const float CI0 = 4166.666666666667f;         // SPONT/PIREST
    const float CL0 = 5000.0f;
    const float CG  = 6666.6669921875f;           // f32-exact per reference
    const float CLC = A_L * PGc * CG;

    __shared__ float wt[4][6];   // per-wave tile-total maps (m00,m01,m10,m11,v0,v1)

    float CIr = CI0, CLr = CL0;            // running state entering current round
    const bool active = (tid < ACT);

    for (int r = 0; r < ROUNDS; ++r) {
        const int t0 = r * TILE + tid * CS;

        // ---- pass 1: softplus + compose this chunk's affine map; keep ppi in regs ----
        float ppi_[CS];
        float m00 = 1.f, m01 = 0.f, m10 = 0.f, m11 = 1.f, v0 = 0.f, v1 = 0.f;

        if (active) {
            const float4* src = reinterpret_cast<const float4*>(ihcl + base + t0);
            float4 q0 = src[0], q1 = src[1], q2 = src[2], q3 = src[3];
            float xs[CS] = {q0.x,q0.y,q0.z,q0.w, q1.x,q1.y,q1.z,q1.w,
                            q2.x,q2.y,q2.z,q2.w, q3.x,q3.y,q3.z,q3.w};
            #pragma unroll
            for (int e = 0; e < CS; ++e) {
                float ppi = softplus_ppi(xs[e]);
                ppi_[e] = ppi;
                bool skip = (e == 0) && (r == 0) && (tid == 0);  // global t=0: identity
                if (!skip) {
                    float al = 1.0f - A_I * (ppi + PLc);
                    // A = [[al, BE], [GA*al, GA*BE + DE]], b = (0, CLC)
                    float nm00 = al * m00 + BE * m10;
                    float nm01 = al * m01 + BE * m11;
                    float nv0  = al * v0  + BE * v1;
                    m10 = GA * nm00 + DE * m10;
                    m11 = GA * nm01 + DE * m11;
                    v1  = GA * nv0  + DE * v1 + CLC;
                    m00 = nm00; m01 = nm01; v0 = nv0;
                }
            }
        }

        // ---- wave-level inclusive scan of affine maps (register-only, no barriers) ----
        #pragma unroll
        for (int d = 1; d < 64; d <<= 1) {
            float a00 = __shfl_up(m00, d);
            float a01 = __shfl_up(m01, d);
            float a10 = __shfl_up(m10, d);
            float a11 = __shfl_up(m11, d);
            float av0 = __shfl_up(v0,  d);
            float av1 = __shfl_up(v1,  d);
            if (lane >= d) {
                // mine after left: M = M_mine*M_left ; v = M_mine*v_left + v_mine
                float r00 = m00*a00 + m01*a10;
                float r01 = m00*a01 + m01*a11;
                float r10 = m10*a00 + m11*a10;
                float r11 = m10*a01 + m11*a11;
                float rv0 = m00*av0 + m01*av1 + v0;
                float rv1 = m10*av0 + m11*av1 + v1;
                m00=r00; m01=r01; m10=r10; m11=r11; v0=rv0; v1=rv1;
            }
        }

        // ---- cross-wave exchange: lane 63 publishes wave total ----
        if (lane == 63) {
            wt[wv][0]=m00; wt[wv][1]=m01; wt[wv][2]=m10;
            wt[wv][3]=m11; wt[wv][4]=v0;  wt[wv][5]=v1;
        }
        __syncthreads();

        // exclusive in-wave prefix (shift inclusive by one lane)
        float e00 = __shfl_up(m00, 1), e01 = __shfl_up(m01, 1);
        float e10 = __shfl_up(m10, 1), e11 = __shfl_up(m11, 1);
        float ev0 = __shfl_up(v0,  1), ev1 = __shfl_up(v1,  1);

        // start state of my chunk: apply preceding waves' totals, then my
        // in-wave exclusive map — matrix*VECTOR applies only.
        float CIs = CIr, CLs = CLr;
        for (int ww = 0; ww < wv; ++ww) {
            float a = CIs;
            CIs = wt[ww][0]*a + wt[ww][1]*CLs + wt[ww][4];
            CLs = wt[ww][2]*a + wt[ww][3]*CLs + wt[ww][5];
        }
        if (lane > 0) {
            float a = CIs;
            CIs = e00*a + e01*CLs + ev0;
            CLs = e10*a + e11*CLs + ev1;
        }

        // running state for next round: all 4 wave totals applied in order
        float nCI = CIr, nCL = CLr;
        #pragma unroll
        for (int ww = 0; ww < 4; ++ww) {
            float a = nCI;
            nCI = wt[ww][0]*a + wt[ww][1]*nCL + wt[ww][4];
            nCL = wt[ww][2]*a + wt[ww][3]*nCL + wt[ww][5];
        }

        // ---- replay chunk with exact reference update, write output ----
        if (active) {
            float CI = CIs, CL = CLs;
            float4* dst = reinterpret_cast<float4*>(out + base + t0);
            #pragma unroll
            for (int j = 0; j < CS / 4; ++j) {
                float os[4];
                #pragma unroll
                for (int q = 0; q < 4; ++q) {
                    int e = j * 4 + q;
                    if (e == 0 && r == 0 && tid == 0) { os[q] = 50.0f; continue; }
                    float ppi = ppi_[e];
                    CI = CI + A_I * (-ppi * CI + PLc * (CL - CI));
                    CL = CL + A_L * (-PLc * (CL - CI) + PGc * (CG - CL));
                    os[q] = CI * ppi;
                }
                dst[j] = make_float4(os[0], os[1], os[2], os[3]);
            }
        }

        CIr = nCI; CLr = nCL;
        __syncthreads();   // protect wt[] before next round's lane-63 writes
    }
}

extern "C" void kernel_launch(void* const* d_in, const int* in_sizes, int n_in,
                              void* d_out, int out_size, void* d_ws, size_t ws_size,
                              hipStream_t stream) {
    const float* ihcl = (const float*)d_in[0];
    float* out = (float*)d_out;
    na_scan_kernel<<<NBC, NTHREADS, 0, stream>>>(ihcl, out);
}